// Round 1
// 229.434 us; speedup vs baseline: 1.8635x; 1.8635x over previous
//
#include <hip/hip_runtime.h>

typedef short bf16x8 __attribute__((ext_vector_type(8)));
typedef float f32x4 __attribute__((ext_vector_type(4)));
typedef unsigned short u16;
typedef unsigned int u32;

static __device__ __forceinline__ u16 f2bf(float f) {
  u32 u = __builtin_bit_cast(u32, f);
  u32 r = (u + 0x7FFFu + ((u >> 16) & 1u)) >> 16;  // RNE
  return (u16)r;
}

// ---- kernel 0: one-time f32 -> bf16 weight conversion + FRAGMENT SWIZZLE ----
// wqkv chunks (cid < 24576): tile = cid>>9 (tile = s*16+h*2+u), k = (cid>>6)&7,
//   lane = cid&63; 16B chunk = W[tile*16+(lane&15)][k*32+(lane>>4)*8 .. +8],
//   stored at wbf + cid*8 (linear).
// wproj (pid < 8192): mt = pid>>9, h = (pid>>6)&7, lane = pid&63 — stored
//   HEAD-MAJOR so each head's proj slice is one contiguous 16 KB stage unit:
//   dst chunk = 24576 + h*1024 + mt*64 + lane.
__global__ __launch_bounds__(256) void k_conv(
    const float* __restrict__ wqkv, const float* __restrict__ wproj,
    u16* __restrict__ wbf) {
  const int cid = blockIdx.x * 256 + threadIdx.x;  // 128 blocks -> 32768 chunks
  const float* src;
  int dst;
  if (cid < 24576) {
    const int tile = cid >> 9, rem = cid & 511;
    const int k = rem >> 6, lane = rem & 63;
    src = wqkv + (size_t)(tile * 16 + (lane & 15)) * 256 + k * 32 + (lane >> 4) * 8;
    dst = cid;
  } else {
    const int pid = cid - 24576;
    const int mt = pid >> 9, rem = pid & 511;
    const int h = rem >> 6, lane = rem & 63;
    src = wproj + (size_t)(mt * 16 + (lane & 15)) * 256 + h * 32 + (lane >> 4) * 8;
    dst = 24576 + h * 1024 + mt * 64 + lane;
  }
  float4 f0 = *(const float4*)(src);
  float4 f1 = *(const float4*)(src + 4);
  ushort4 a, b;
  a.x = f2bf(f0.x); a.y = f2bf(f0.y); a.z = f2bf(f0.z); a.w = f2bf(f0.w);
  b.x = f2bf(f1.x); b.y = f2bf(f1.y); b.z = f2bf(f1.z); b.w = f2bf(f1.w);
  *(ushort4*)(wbf + (size_t)dst * 8) = a;
  *(ushort4*)(wbf + (size_t)dst * 8 + 4) = b;
}

// LDS map (u16 units), time-disjoint overlays:
//   BUF0 [0,8192)      weight stage buffer 0 (16 KB)
//   BUF1 [8192,16384)  weight stage buffer 1 (16 KB)
//   XB   [8192,25088)  X [64][264] (phase 1 only; dead before BUF1/attn used)
//   QH 16384 | KH 18944 | VTH 21504 | PH 23808 (+wv*1152)   attn region
#define BUF0 0
#define BUF1 8192
#define XB 8192
#define QH 16384
#define KH 18944
#define VTH 21504
#define PH 23808
#define LDS_TOT 28416

#define MEMF() asm volatile("" ::: "memory")
#define BAR()                        \
  do {                               \
    MEMF();                          \
    __builtin_amdgcn_s_barrier();    \
    MEMF();                          \
  } while (0)
#define WVM4() asm volatile("s_waitcnt vmcnt(4)" ::: "memory")
#define WVM0() asm volatile("s_waitcnt vmcnt(0)" ::: "memory")
#define WLG0() asm volatile("s_waitcnt lgkmcnt(0)" ::: "memory")

#define GL2LDS(gp, lp)                                   \
  __builtin_amdgcn_global_load_lds(                      \
      (__attribute__((address_space(1))) void*)(gp),     \
      (__attribute__((address_space(3))) void*)(lp), 16, 0, 0)

// stage one 8192-u16 (16 KB) unit: 4 x global_load_lds dwordx4 per thread.
// LDS dest is wave-uniform base + lane*16 (linear), matching the pre-swizzled
// global layout, so a verbatim copy preserves fragment order.
static __device__ __forceinline__ void stage_unit(const u16* g, u16* l, int t) {
#pragma unroll
  for (int j = 0; j < 4; ++j) {
    const int off = (j * 256 + t) * 8;
    GL2LDS(g + off, l + off);
  }
}

__global__ __launch_bounds__(256, 2) void k_fused(
    const float* __restrict__ x, const u16* __restrict__ wbf,
    const int* __restrict__ shiftp, float* __restrict__ out) {
  __shared__ u16 LDS[LDS_TOT];
  // XCD-locality swizzle: the 8 windows sharing x/out cache lines (same b,wh)
  // get block IDs congruent mod 128 -> same XCD under round-robin dispatch.
  const int blk = blockIdx.x;
  const int win = ((blk & 127) << 3) | (blk >> 7);  // b*64 + wh*8 + ww
  const int b = win >> 6, wh = (win >> 3) & 7, ww = win & 7;
  const int off = (shiftp[0] != 0) ? 4 : 0;
  const int t = threadIdx.x;

  // ---- phase 1: stage rolled X into LDS [pos][c] (f32 -> bf16) ----
  {
    u16* X = LDS + XB;
    const int wr = t & 7;
    const int h = ((wh << 3) + wr + off) & 63;
    const int w0 = ((ww << 3) + off) & 63;  // 4-aligned -> no wrap inside run
    const int w1 = ((ww << 3) + off + 4) & 63;
    const int p0 = wr << 3;
#pragma unroll
    for (int it = 0; it < 8; ++it) {
      const int c = (t >> 3) + (it << 5);
      const float* src = x + ((size_t)(b * 256 + c) * 64 + h) * 64;
      float4 v0 = *(const float4*)(src + w0);
      float4 v1 = *(const float4*)(src + w1);
      X[(p0 + 0) * 264 + c] = f2bf(v0.x);
      X[(p0 + 1) * 264 + c] = f2bf(v0.y);
      X[(p0 + 2) * 264 + c] = f2bf(v0.z);
      X[(p0 + 3) * 264 + c] = f2bf(v0.w);
      X[(p0 + 4) * 264 + c] = f2bf(v1.x);
      X[(p0 + 5) * 264 + c] = f2bf(v1.y);
      X[(p0 + 6) * 264 + c] = f2bf(v1.z);
      X[(p0 + 7) * 264 + c] = f2bf(v1.w);
    }
  }
  __syncthreads();  // X ready (full drain OK here; also drains x loads)

  // prefetch unit 0 = (h0, Q-tiles) into BUF0 (disjoint from live X)
  stage_unit(wbf, LDS + BUF0, t);

  const int lane = t & 63, wv = t >> 6;  // wave wv owns pos rows wv*16..+15
  const int l15 = lane & 15, quad = lane >> 4;
  const int pos0 = wv * 16 + quad * 4;

  bf16x8 af[8];
#pragma unroll
  for (int k = 0; k < 8; ++k)
    af[k] = *(const bf16x8*)&LDS[XB + (wv * 16 + l15) * 264 + quad * 8 + k * 32];
  WLG0();
  BAR();  // X dead everywhere; BUF1/attn regions may now be written

  // prefetch unit 1 = (h0, K-tiles) into BUF1
  stage_unit(wbf + (size_t)16 * 4096, LDS + BUF1, t);

  f32x4 accP[16];  // proj acc: tile mt rows quad*4+r (c_out), col l15 (pos)
#pragma unroll
  for (int mt = 0; mt < 16; ++mt) accP[mt] = (f32x4){0.f, 0.f, 0.f, 0.f};

  const float scale = 0.17677669529663687f;  // 1/sqrt(32)
  u16* Pw = LDS + PH + wv * 1152;            // per-wave P [16][72]

  // 32 pipeline units (4 per head: Q, K, V, proj). Double-buffered staging:
  // at each unit entry exactly 2 stages are outstanding -> vmcnt(4) drains the
  // unit about to be computed while the next stays in flight (T3/T4 pattern;
  // raw s_barrier, never __syncthreads, so prefetches survive barriers).
#pragma unroll 1
  for (int h = 0; h < 8; ++h) {
    const u16* s_v = wbf + (size_t)(32 + h * 2) * 4096;        // unit 4h+2 (s=2)
    const u16* s_pj = wbf + 196608 + (size_t)h * 8192;         // unit 4h+3 (proj)
    const u16* s_nq = wbf + (size_t)((h + 1) * 2) * 4096;      // unit 4h+4 (s=0,h+1)
    const u16* s_nk = wbf + (size_t)(16 + (h + 1) * 2) * 4096; // unit 4h+5 (s=1,h+1)

    // ---- unit 4h+0: Q tiles (BUF0) ----
    WVM4();
    BAR();
#pragma unroll
    for (int u = 0; u < 2; ++u) {
      const u16* wb_ = LDS + BUF0 + u * 4096 + lane * 8;
      f32x4 acc = {0.f, 0.f, 0.f, 0.f};
#pragma unroll
      for (int k = 0; k < 8; ++k)
        acc = __builtin_amdgcn_mfma_f32_16x16x32_bf16(
            af[k], *(const bf16x8*)(wb_ + k * 512), acc, 0, 0, 0);
#pragma unroll
      for (int r = 0; r < 4; ++r)
        LDS[QH + (pos0 + r) * 40 + u * 16 + l15] = f2bf(acc[r]);
    }
    WLG0();
    BAR();
    stage_unit(s_v, LDS + BUF0, t);

    // ---- unit 4h+1: K tiles (BUF1) ----
    WVM4();
    BAR();
#pragma unroll
    for (int u = 0; u < 2; ++u) {
      const u16* wb_ = LDS + BUF1 + u * 4096 + lane * 8;
      f32x4 acc = {0.f, 0.f, 0.f, 0.f};
#pragma unroll
      for (int k = 0; k < 8; ++k)
        acc = __builtin_amdgcn_mfma_f32_16x16x32_bf16(
            af[k], *(const bf16x8*)(wb_ + k * 512), acc, 0, 0, 0);
#pragma unroll
      for (int r = 0; r < 4; ++r)
        LDS[KH + (pos0 + r) * 40 + u * 16 + l15] = f2bf(acc[r]);
    }
    WLG0();
    BAR();
    stage_unit(s_pj, LDS + BUF1, t);

    // ---- unit 4h+2: V tiles (BUF0), stored transposed [hd][pos] ----
    WVM4();
    BAR();
#pragma unroll
    for (int u = 0; u < 2; ++u) {
      const u16* wb_ = LDS + BUF0 + u * 4096 + lane * 8;
      f32x4 acc = {0.f, 0.f, 0.f, 0.f};
#pragma unroll
      for (int k = 0; k < 8; ++k)
        acc = __builtin_amdgcn_mfma_f32_16x16x32_bf16(
            af[k], *(const bf16x8*)(wb_ + k * 512), acc, 0, 0, 0);
      ushort4 pk;
      pk.x = f2bf(acc[0]);
      pk.y = f2bf(acc[1]);
      pk.z = f2bf(acc[2]);
      pk.w = f2bf(acc[3]);
      *(ushort4*)&LDS[VTH + (u * 16 + l15) * 72 + pos0] = pk;
    }
    WLG0();
    BAR();
    if (h < 7) stage_unit(s_nq, LDS + BUF0, t);

    // ---- unit 4h+3: attention (Q/K/V ready) + proj (BUF1) ----
    if (h < 7) {
      WVM4();
    } else {
      WVM0();
    }
    BAR();
    bf16x8 aq = *(const bf16x8*)&LDS[QH + (wv * 16 + l15) * 40 + quad * 8];
    f32x4 sc[4];
#pragma unroll
    for (int nt = 0; nt < 4; ++nt) {
      bf16x8 bk = *(const bf16x8*)&LDS[KH + (nt * 16 + l15) * 40 + quad * 8];
      f32x4 z = {0.f, 0.f, 0.f, 0.f};
      sc[nt] = __builtin_amdgcn_mfma_f32_16x16x32_bf16(aq, bk, z, 0, 0, 0);
    }
#pragma unroll
    for (int r = 0; r < 4; ++r) {
      float mx = -1e30f;
#pragma unroll
      for (int nt = 0; nt < 4; ++nt) mx = fmaxf(mx, sc[nt][r]);
      mx = fmaxf(mx, __shfl_xor(mx, 1));
      mx = fmaxf(mx, __shfl_xor(mx, 2));
      mx = fmaxf(mx, __shfl_xor(mx, 4));
      mx = fmaxf(mx, __shfl_xor(mx, 8));  // row spans the 16-lane group
      float p[4], sum = 0.f;
#pragma unroll
      for (int nt = 0; nt < 4; ++nt) {
        p[nt] = __expf((sc[nt][r] - mx) * scale);
        sum += p[nt];
      }
      sum += __shfl_xor(sum, 1);
      sum += __shfl_xor(sum, 2);
      sum += __shfl_xor(sum, 4);
      sum += __shfl_xor(sum, 8);
      const float is = 1.f / sum;
#pragma unroll
      for (int nt = 0; nt < 4; ++nt)
        Pw[(quad * 4 + r) * 72 + nt * 16 + l15] = f2bf(p[nt] * is);
    }
    // PV
    f32x4 oa[2];
    oa[0] = (f32x4){0.f, 0.f, 0.f, 0.f};
    oa[1] = (f32x4){0.f, 0.f, 0.f, 0.f};
#pragma unroll
    for (int kk = 0; kk < 2; ++kk) {
      bf16x8 ap = *(const bf16x8*)&Pw[l15 * 72 + kk * 32 + quad * 8];
#pragma unroll
      for (int n2 = 0; n2 < 2; ++n2) {
        bf16x8 bv =
            *(const bf16x8*)&LDS[VTH + (n2 * 16 + l15) * 72 + kk * 32 + quad * 8];
        oa[n2] = __builtin_amdgcn_mfma_f32_16x16x32_bf16(ap, bv, oa[n2], 0, 0, 0);
      }
    }
    // O overwrites own Q rows (wave-private)
#pragma unroll
    for (int n2 = 0; n2 < 2; ++n2)
#pragma unroll
      for (int r = 0; r < 4; ++r)
        LDS[QH + (pos0 + r) * 40 + n2 * 16 + l15] = f2bf(oa[n2][r]);
    // proj accumulate: A = Wproj head-slice (staged in BUF1), B = O rows
    bf16x8 bo = *(const bf16x8*)&LDS[QH + (wv * 16 + l15) * 40 + quad * 8];
#pragma unroll
    for (int mt = 0; mt < 16; ++mt) {
      bf16x8 aw = *(const bf16x8*)&LDS[BUF1 + mt * 512 + lane * 8];
      accP[mt] = __builtin_amdgcn_mfma_f32_16x16x32_bf16(aw, bo, accP[mt], 0, 0, 0);
    }
    WLG0();
    BAR();
    if (h < 7) stage_unit(s_nk, LDS + BUF1, t);
  }

  // ---- epilogue: C[c_out][pos] -> out[b][c][h][w] with roll(+4,+4) ----
  const int pos = wv * 16 + l15;
  const int hco = ((wh << 3) + (pos >> 3) + off) & 63;
  const int wco = ((ww << 3) + (pos & 7) + off) & 63;
#pragma unroll
  for (int mt = 0; mt < 16; ++mt)
#pragma unroll
    for (int r = 0; r < 4; ++r) {
      const int c = mt * 16 + quad * 4 + r;
      out[((size_t)(b * 256 + c) << 12) + (hco << 6) + wco] = accP[mt][r];
    }
}

extern "C" void kernel_launch(void* const* d_in, const int* in_sizes, int n_in,
                              void* d_out, int out_size, void* d_ws, size_t ws_size,
                              hipStream_t stream) {
  const float* x = (const float*)d_in[0];      // [16,256,64,64] f32
  const float* wqkv = (const float*)d_in[1];   // [768,256] f32
  const float* wproj = (const float*)d_in[2];  // [256,256] f32
  const int* shiftp = (const int*)d_in[3];     // scalar
  float* outp = (float*)d_out;                 // [16,256,64,64] f32
  u16* wbf = (u16*)d_ws;                       // 262144 u16 = 512 KB scratch
  hipLaunchKernelGGL(k_conv, dim3(128), dim3(256), 0, stream, wqkv, wproj, wbf);
  hipLaunchKernelGGL(k_fused, dim3(1024), dim3(256), 0, stream, x, wbf, shiftp, outp);
}

// Round 2
// 225.334 us; speedup vs baseline: 1.8974x; 1.0182x over previous
//
#include <hip/hip_runtime.h>

typedef short bf16x8 __attribute__((ext_vector_type(8)));
typedef float f32x4 __attribute__((ext_vector_type(4)));
typedef unsigned short u16;
typedef unsigned int u32;

static __device__ __forceinline__ u16 f2bf(float f) {
  u32 u = __builtin_bit_cast(u32, f);
  u32 r = (u + 0x7FFFu + ((u >> 16) & 1u)) >> 16;  // RNE
  return (u16)r;
}

// ---- kernel 0: one-time f32 -> bf16 weight conversion + FRAGMENT SWIZZLE ----
// wqkv chunks (cid < 24576): tile = cid>>9 (tile = s*16+h*2+u), k = (cid>>6)&7,
//   lane = cid&63; 16B chunk = W[tile*16+(lane&15)][k*32+(lane>>4)*8 .. +8],
//   stored at wbf + cid*8 (linear).
// wproj (pid < 8192): mt = pid>>9, h = (pid>>6)&7, lane = pid&63 — stored
//   HEAD-MAJOR so each head's proj slice is contiguous (two 8 KB halves):
//   dst chunk = 24576 + h*1024 + mt*64 + lane.
__global__ __launch_bounds__(256) void k_conv(
    const float* __restrict__ wqkv, const float* __restrict__ wproj,
    u16* __restrict__ wbf) {
  const int cid = blockIdx.x * 256 + threadIdx.x;  // 128 blocks -> 32768 chunks
  const float* src;
  int dst;
  if (cid < 24576) {
    const int tile = cid >> 9, rem = cid & 511;
    const int k = rem >> 6, lane = rem & 63;
    src = wqkv + (size_t)(tile * 16 + (lane & 15)) * 256 + k * 32 + (lane >> 4) * 8;
    dst = cid;
  } else {
    const int pid = cid - 24576;
    const int mt = pid >> 9, rem = pid & 511;
    const int h = rem >> 6, lane = rem & 63;
    src = wproj + (size_t)(mt * 16 + (lane & 15)) * 256 + h * 32 + (lane >> 4) * 8;
    dst = 24576 + h * 1024 + mt * 64 + lane;
  }
  float4 f0 = *(const float4*)(src);
  float4 f1 = *(const float4*)(src + 4);
  ushort4 a, b;
  a.x = f2bf(f0.x); a.y = f2bf(f0.y); a.z = f2bf(f0.z); a.w = f2bf(f0.w);
  b.x = f2bf(f1.x); b.y = f2bf(f1.y); b.z = f2bf(f1.z); b.w = f2bf(f1.w);
  *(ushort4*)(wbf + (size_t)dst * 8) = a;
  *(ushort4*)(wbf + (size_t)dst * 8 + 4) = b;
}

// LDS map (u16 units), time-disjoint overlays — total 40448 B -> 4 blocks/CU:
//   BUF0 [0,4096)      weight stage buffer 0 (8 KB)
//   BUF1 [4096,8192)   weight stage buffer 1 (8 KB)
//   XB   [0,16896)     X [64][264] (phase 1 only; dead before any DMA issues)
//   QH 8192 | KH 10752 | VTH 13312 | PH 15616 (+wv*1152)   attn region
#define BUF0 0
#define BUF1 4096
#define XB 0
#define QH 8192
#define KH 10752
#define VTH 13312
#define PH 15616
#define LDS_TOT 20224

#define MEMF() asm volatile("" ::: "memory")
#define BAR()                        \
  do {                               \
    MEMF();                          \
    __builtin_amdgcn_s_barrier();    \
    MEMF();                          \
  } while (0)
#define WVM2() asm volatile("s_waitcnt vmcnt(2)" ::: "memory")
#define WVM0() asm volatile("s_waitcnt vmcnt(0)" ::: "memory")
#define WLG0() asm volatile("s_waitcnt lgkmcnt(0)" ::: "memory")

#define GL2LDS(gp, lp)                                   \
  __builtin_amdgcn_global_load_lds(                      \
      (__attribute__((address_space(1))) void*)(gp),     \
      (__attribute__((address_space(3))) void*)(lp), 16, 0, 0)

// stage one 4096-u16 (8 KB) unit: 2 x global_load_lds dwordx4 per thread.
// LDS dest is wave-uniform base + lane*16 (linear), matching the pre-swizzled
// global layout, so a verbatim copy preserves fragment order.
static __device__ __forceinline__ void stage_half(const u16* g, u16* l, int t) {
#pragma unroll
  for (int j = 0; j < 2; ++j) {
    const int off = (j * 256 + t) * 8;
    GL2LDS(g + off, l + off);
  }
}

// one 16-c_out QKV tile from staged buffer BUFB -> QH/KH row store at col U*16
#define QKV_TILE(BUFB, DSTB, U)                                           \
  do {                                                                    \
    const u16* wb_ = LDS + (BUFB) + lane * 8;                             \
    f32x4 acc = {0.f, 0.f, 0.f, 0.f};                                     \
    _Pragma("unroll") for (int k = 0; k < 8; ++k) acc =                   \
        __builtin_amdgcn_mfma_f32_16x16x32_bf16(                          \
            af[k], *(const bf16x8*)(wb_ + k * 512), acc, 0, 0, 0);        \
    _Pragma("unroll") for (int r = 0; r < 4; ++r)                         \
        LDS[(DSTB) + (pos0 + r) * 40 + (U) * 16 + l15] = f2bf(acc[r]);    \
  } while (0)

// one 16-c_out V tile -> VTH transposed [hd][pos]
#define V_TILE(BUFB, U)                                                   \
  do {                                                                    \
    const u16* wb_ = LDS + (BUFB) + lane * 8;                             \
    f32x4 acc = {0.f, 0.f, 0.f, 0.f};                                     \
    _Pragma("unroll") for (int k = 0; k < 8; ++k) acc =                   \
        __builtin_amdgcn_mfma_f32_16x16x32_bf16(                          \
            af[k], *(const bf16x8*)(wb_ + k * 512), acc, 0, 0, 0);        \
    ushort4 pk;                                                           \
    pk.x = f2bf(acc[0]); pk.y = f2bf(acc[1]);                             \
    pk.z = f2bf(acc[2]); pk.w = f2bf(acc[3]);                             \
    *(ushort4*)&LDS[VTH + ((U) * 16 + l15) * 72 + pos0] = pk;             \
  } while (0)

__global__ __launch_bounds__(256, 4) void k_fused(
    const float* __restrict__ x, const u16* __restrict__ wbf,
    const int* __restrict__ shiftp, float* __restrict__ out) {
  __shared__ u16 LDS[LDS_TOT];
  // XCD-locality swizzle: the 8 windows sharing x/out cache lines (same b,wh)
  // get block IDs congruent mod 128 -> same XCD under round-robin dispatch.
  const int blk = blockIdx.x;
  const int win = ((blk & 127) << 3) | (blk >> 7);  // b*64 + wh*8 + ww
  const int b = win >> 6, wh = (win >> 3) & 7, ww = win & 7;
  const int off = (shiftp[0] != 0) ? 4 : 0;
  const int t = threadIdx.x;

  // ---- phase 1: stage rolled X into LDS [pos][c] (f32 -> bf16) ----
  {
    u16* X = LDS + XB;
    const int wr = t & 7;
    const int h = ((wh << 3) + wr + off) & 63;
    const int w0 = ((ww << 3) + off) & 63;  // 4-aligned -> no wrap inside run
    const int w1 = ((ww << 3) + off + 4) & 63;
    const int p0 = wr << 3;
#pragma unroll
    for (int it = 0; it < 8; ++it) {
      const int c = (t >> 3) + (it << 5);
      const float* src = x + ((size_t)(b * 256 + c) * 64 + h) * 64;
      float4 v0 = *(const float4*)(src + w0);
      float4 v1 = *(const float4*)(src + w1);
      X[(p0 + 0) * 264 + c] = f2bf(v0.x);
      X[(p0 + 1) * 264 + c] = f2bf(v0.y);
      X[(p0 + 2) * 264 + c] = f2bf(v0.z);
      X[(p0 + 3) * 264 + c] = f2bf(v0.w);
      X[(p0 + 4) * 264 + c] = f2bf(v1.x);
      X[(p0 + 5) * 264 + c] = f2bf(v1.y);
      X[(p0 + 6) * 264 + c] = f2bf(v1.z);
      X[(p0 + 7) * 264 + c] = f2bf(v1.w);
    }
  }
  __syncthreads();  // X ready (full drain OK; also drains x loads -> vmcnt 0)

  const int lane = t & 63, wv = t >> 6;  // wave wv owns pos rows wv*16..+15
  const int l15 = lane & 15, quad = lane >> 4;
  const int pos0 = wv * 16 + quad * 4;

  bf16x8 af[8];
#pragma unroll
  for (int k = 0; k < 8; ++k)
    af[k] = *(const bf16x8*)&LDS[XB + (wv * 16 + l15) * 264 + quad * 8 + k * 32];
  WLG0();
  BAR();  // X fully read everywhere; BUF0/BUF1/attn regions may now be written

  // prologue prefetch: unit 0 (h0 Q u0) -> BUF0, unit 1 (h0 Q u1) -> BUF1
  stage_half(wbf, LDS + BUF0, t);
  stage_half(wbf + 4096, LDS + BUF1, t);

  f32x4 accP[16];  // proj acc: tile mt rows quad*4+r (c_out), col l15 (pos)
#pragma unroll
  for (int mt = 0; mt < 16; ++mt) accP[mt] = (f32x4){0.f, 0.f, 0.f, 0.f};

  const float scale = 0.17677669529663687f;  // 1/sqrt(32)
  u16* Pw = LDS + PH + wv * 1152;            // per-wave P [16][72]

  // 64 pipeline units (8 per head: Qu0,Qu1,Ku0,Ku1,Vu0,Vu1,pj0,pj1), 8 KB
  // each, double-buffered by unit parity. Stage for unit n issues at end of
  // unit n-2; at each unit entry 2 stages (4 loads) are outstanding ->
  // vmcnt(2) drains the current unit's loads while the next stays in flight.
  // Raw s_barrier (never __syncthreads) so prefetches survive barriers.
#pragma unroll 1
  for (int h = 0; h < 8; ++h) {
    // ---- unit 8h+0: Q u0 (BUF0) ----
    WVM2(); BAR();
    QKV_TILE(BUF0, QH, 0);
    WLG0(); BAR();
    stage_half(wbf + (size_t)(16 + h * 2) * 4096, LDS + BUF0, t);  // K u0
    // ---- unit 8h+1: Q u1 (BUF1) ----
    WVM2(); BAR();
    QKV_TILE(BUF1, QH, 1);
    WLG0(); BAR();
    stage_half(wbf + (size_t)(17 + h * 2) * 4096, LDS + BUF1, t);  // K u1
    // ---- unit 8h+2: K u0 (BUF0) ----
    WVM2(); BAR();
    QKV_TILE(BUF0, KH, 0);
    WLG0(); BAR();
    stage_half(wbf + (size_t)(32 + h * 2) * 4096, LDS + BUF0, t);  // V u0
    // ---- unit 8h+3: K u1 (BUF1) ----
    WVM2(); BAR();
    QKV_TILE(BUF1, KH, 1);
    WLG0(); BAR();
    stage_half(wbf + (size_t)(33 + h * 2) * 4096, LDS + BUF1, t);  // V u1
    // ---- unit 8h+4: V u0 (BUF0) ----
    WVM2(); BAR();
    V_TILE(BUF0, 0);
    WLG0(); BAR();
    stage_half(wbf + 196608 + (size_t)h * 8192, LDS + BUF0, t);    // pj0
    // ---- unit 8h+5: V u1 (BUF1) ----
    WVM2(); BAR();
    V_TILE(BUF1, 1);
    WLG0(); BAR();
    stage_half(wbf + 196608 + (size_t)h * 8192 + 4096, LDS + BUF1, t);  // pj1
    // ---- unit 8h+6: attention (Q/K/V ready) + proj mt 0..7 (BUF0) ----
    WVM2(); BAR();
    {
      bf16x8 aq = *(const bf16x8*)&LDS[QH + (wv * 16 + l15) * 40 + quad * 8];
      f32x4 sc[4];
#pragma unroll
      for (int nt = 0; nt < 4; ++nt) {
        bf16x8 bk = *(const bf16x8*)&LDS[KH + (nt * 16 + l15) * 40 + quad * 8];
        f32x4 z = {0.f, 0.f, 0.f, 0.f};
        sc[nt] = __builtin_amdgcn_mfma_f32_16x16x32_bf16(aq, bk, z, 0, 0, 0);
      }
#pragma unroll
      for (int r = 0; r < 4; ++r) {
        float mx = -1e30f;
#pragma unroll
        for (int nt = 0; nt < 4; ++nt) mx = fmaxf(mx, sc[nt][r]);
        mx = fmaxf(mx, __shfl_xor(mx, 1));
        mx = fmaxf(mx, __shfl_xor(mx, 2));
        mx = fmaxf(mx, __shfl_xor(mx, 4));
        mx = fmaxf(mx, __shfl_xor(mx, 8));  // row spans the 16-lane group
        float p[4], sum = 0.f;
#pragma unroll
        for (int nt = 0; nt < 4; ++nt) {
          p[nt] = __expf((sc[nt][r] - mx) * scale);
          sum += p[nt];
        }
        sum += __shfl_xor(sum, 1);
        sum += __shfl_xor(sum, 2);
        sum += __shfl_xor(sum, 4);
        sum += __shfl_xor(sum, 8);
        const float is = 1.f / sum;
#pragma unroll
        for (int nt = 0; nt < 4; ++nt)
          Pw[(quad * 4 + r) * 72 + nt * 16 + l15] = f2bf(p[nt] * is);
      }
      // PV
      f32x4 oa[2];
      oa[0] = (f32x4){0.f, 0.f, 0.f, 0.f};
      oa[1] = (f32x4){0.f, 0.f, 0.f, 0.f};
#pragma unroll
      for (int kk = 0; kk < 2; ++kk) {
        bf16x8 ap = *(const bf16x8*)&Pw[l15 * 72 + kk * 32 + quad * 8];
#pragma unroll
        for (int n2 = 0; n2 < 2; ++n2) {
          bf16x8 bv =
              *(const bf16x8*)&LDS[VTH + (n2 * 16 + l15) * 72 + kk * 32 + quad * 8];
          oa[n2] = __builtin_amdgcn_mfma_f32_16x16x32_bf16(ap, bv, oa[n2], 0, 0, 0);
        }
      }
      // O overwrites own Q rows (wave-private)
#pragma unroll
      for (int n2 = 0; n2 < 2; ++n2)
#pragma unroll
        for (int r = 0; r < 4; ++r)
          LDS[QH + (pos0 + r) * 40 + n2 * 16 + l15] = f2bf(oa[n2][r]);
      // proj accumulate, first half: A = Wproj tiles 0..7 (BUF0), B = O rows
      bf16x8 bo = *(const bf16x8*)&LDS[QH + (wv * 16 + l15) * 40 + quad * 8];
#pragma unroll
      for (int mt = 0; mt < 8; ++mt) {
        bf16x8 aw = *(const bf16x8*)&LDS[BUF0 + mt * 512 + lane * 8];
        accP[mt] = __builtin_amdgcn_mfma_f32_16x16x32_bf16(aw, bo, accP[mt], 0, 0, 0);
      }
      WLG0(); BAR();
      if (h < 7)
        stage_half(wbf + (size_t)((h + 1) * 2) * 4096, LDS + BUF0, t);  // next Q u0
      // ---- unit 8h+7: proj mt 8..15 (BUF1) ----
      if (h < 7) { WVM2(); } else { WVM0(); }
      BAR();
#pragma unroll
      for (int mt = 0; mt < 8; ++mt) {
        bf16x8 aw = *(const bf16x8*)&LDS[BUF1 + mt * 512 + lane * 8];
        accP[8 + mt] =
            __builtin_amdgcn_mfma_f32_16x16x32_bf16(aw, bo, accP[8 + mt], 0, 0, 0);
      }
    }
    WLG0(); BAR();
    if (h < 7)
      stage_half(wbf + (size_t)((h + 1) * 2 + 1) * 4096, LDS + BUF1, t);  // next Q u1
  }

  // ---- epilogue: C[c_out][pos] -> out[b][c][h][w] with roll(+4,+4) ----
  const int pos = wv * 16 + l15;
  const int hco = ((wh << 3) + (pos >> 3) + off) & 63;
  const int wco = ((ww << 3) + (pos & 7) + off) & 63;
#pragma unroll
  for (int mt = 0; mt < 16; ++mt)
#pragma unroll
    for (int r = 0; r < 4; ++r) {
      const int c = mt * 16 + quad * 4 + r;
      out[((size_t)(b * 256 + c) << 12) + (hco << 6) + wco] = accP[mt][r];
    }
}

extern "C" void kernel_launch(void* const* d_in, const int* in_sizes, int n_in,
                              void* d_out, int out_size, void* d_ws, size_t ws_size,
                              hipStream_t stream) {
  const float* x = (const float*)d_in[0];      // [16,256,64,64] f32
  const float* wqkv = (const float*)d_in[1];   // [768,256] f32
  const float* wproj = (const float*)d_in[2];  // [256,256] f32
  const int* shiftp = (const int*)d_in[3];     // scalar
  float* outp = (float*)d_out;                 // [16,256,64,64] f32
  u16* wbf = (u16*)d_ws;                       // 262144 u16 = 512 KB scratch
  hipLaunchKernelGGL(k_conv, dim3(128), dim3(256), 0, stream, wqkv, wproj, wbf);
  hipLaunchKernelGGL(k_fused, dim3(1024), dim3(256), 0, stream, x, wbf, shiftp, outp);
}

// Round 3
// 222.414 us; speedup vs baseline: 1.9223x; 1.0131x over previous
//
#include <hip/hip_runtime.h>

typedef short bf16x8 __attribute__((ext_vector_type(8)));
typedef float f32x4 __attribute__((ext_vector_type(4)));
typedef unsigned short u16;
typedef unsigned int u32;

static __device__ __forceinline__ u16 f2bf(float f) {
  u32 u = __builtin_bit_cast(u32, f);
  u32 r = (u + 0x7FFFu + ((u >> 16) & 1u)) >> 16;  // RNE
  return (u16)r;
}

// ---- kernel 0: one-time f32 -> bf16 weight conversion + FRAGMENT SWIZZLE ----
// wqkv chunks (cid < 24576): tile = cid>>9 (tile = s*16+h*2+u), k = (cid>>6)&7,
//   lane = cid&63; 16B chunk = W[tile*16+(lane&15)][k*32+(lane>>4)*8 .. +8],
//   stored at wbf + cid*8 (linear).
// wproj (pid < 8192): mt = pid>>9, h = (pid>>6)&7, lane = pid&63 — stored
//   HEAD-MAJOR so each head's proj slice is contiguous (two 8 KB halves):
//   dst chunk = 24576 + h*1024 + mt*64 + lane.
__global__ __launch_bounds__(256) void k_conv(
    const float* __restrict__ wqkv, const float* __restrict__ wproj,
    u16* __restrict__ wbf) {
  const int cid = blockIdx.x * 256 + threadIdx.x;  // 128 blocks -> 32768 chunks
  const float* src;
  int dst;
  if (cid < 24576) {
    const int tile = cid >> 9, rem = cid & 511;
    const int k = rem >> 6, lane = rem & 63;
    src = wqkv + (size_t)(tile * 16 + (lane & 15)) * 256 + k * 32 + (lane >> 4) * 8;
    dst = cid;
  } else {
    const int pid = cid - 24576;
    const int mt = pid >> 9, rem = pid & 511;
    const int h = rem >> 6, lane = rem & 63;
    src = wproj + (size_t)(mt * 16 + (lane & 15)) * 256 + h * 32 + (lane >> 4) * 8;
    dst = 24576 + h * 1024 + mt * 64 + lane;
  }
  float4 f0 = *(const float4*)(src);
  float4 f1 = *(const float4*)(src + 4);
  ushort4 a, b;
  a.x = f2bf(f0.x); a.y = f2bf(f0.y); a.z = f2bf(f0.z); a.w = f2bf(f0.w);
  b.x = f2bf(f1.x); b.y = f2bf(f1.y); b.z = f2bf(f1.z); b.w = f2bf(f1.w);
  *(ushort4*)(wbf + (size_t)dst * 8) = a;
  *(ushort4*)(wbf + (size_t)dst * 8 + 4) = b;
}

// LDS map (u16 units), time-disjoint overlays — total 40448 B -> 4 blocks/CU:
//   BUF0 [0,4096)      weight stage buffer 0 (8 KB)
//   BUF1 [4096,8192)   weight stage buffer 1 (8 KB)
//   XB   [0,16896)     X [64][264] (phase 1 only; dead before any DMA issues)
//   QH 8192 | KH 10752 | VTH 13312 | PH 15616 (+wv*1152)   attn region
#define BUF0 0
#define BUF1 4096
#define XB 0
#define QH 8192
#define KH 10752
#define VTH 13312
#define PH 15616
#define LDS_TOT 20224

#define MEMF() asm volatile("" ::: "memory")
// Single-barrier unit entry: drain own DMA (vmcnt) + own LDS ops (lgkm), then
// barrier. After this: (a) all waves' staged slices for THIS unit are visible,
// (b) all waves' reads of the buffer the UPCOMING stage overwrites are done.
// vmcnt(0) is safe: the waited stage was issued before the PREVIOUS unit's
// compute, so it has had a full unit of flight time.
#define ENTRY()                                                      \
  do {                                                               \
    asm volatile("s_waitcnt vmcnt(0) lgkmcnt(0)" ::: "memory");      \
    __builtin_amdgcn_s_barrier();                                    \
    MEMF();                                                          \
  } while (0)

#define GL2LDS(gp, lp)                                   \
  __builtin_amdgcn_global_load_lds(                      \
      (__attribute__((address_space(1))) void*)(gp),     \
      (__attribute__((address_space(3))) void*)(lp), 16, 0, 0)

// stage one 4096-u16 (8 KB) unit: 2 x global_load_lds dwordx4 per thread.
// LDS dest is wave-uniform base + lane*16 (linear), matching the pre-swizzled
// global layout, so a verbatim copy preserves fragment order.
static __device__ __forceinline__ void stage_half(const u16* g, u16* l, int t) {
#pragma unroll
  for (int j = 0; j < 2; ++j) {
    const int off = (j * 256 + t) * 8;
    GL2LDS(g + off, l + off);
  }
}

// one 16-c_out QKV tile from staged buffer BUFB -> QH/KH row store at col U*16
#define QKV_TILE(BUFB, DSTB, U)                                           \
  do {                                                                    \
    const u16* wb_ = LDS + (BUFB) + lane * 8;                             \
    f32x4 acc = {0.f, 0.f, 0.f, 0.f};                                     \
    _Pragma("unroll") for (int k = 0; k < 8; ++k) acc =                   \
        __builtin_amdgcn_mfma_f32_16x16x32_bf16(                          \
            af[k], *(const bf16x8*)(wb_ + k * 512), acc, 0, 0, 0);        \
    _Pragma("unroll") for (int r = 0; r < 4; ++r)                         \
        LDS[(DSTB) + (pos0 + r) * 40 + (U) * 16 + l15] = f2bf(acc[r]);    \
  } while (0)

// one 16-c_out V tile -> VTH transposed [hd][pos]
#define V_TILE(BUFB, U)                                                   \
  do {                                                                    \
    const u16* wb_ = LDS + (BUFB) + lane * 8;                             \
    f32x4 acc = {0.f, 0.f, 0.f, 0.f};                                     \
    _Pragma("unroll") for (int k = 0; k < 8; ++k) acc =                   \
        __builtin_amdgcn_mfma_f32_16x16x32_bf16(                          \
            af[k], *(const bf16x8*)(wb_ + k * 512), acc, 0, 0, 0);        \
    ushort4 pk;                                                           \
    pk.x = f2bf(acc[0]); pk.y = f2bf(acc[1]);                             \
    pk.z = f2bf(acc[2]); pk.w = f2bf(acc[3]);                             \
    *(ushort4*)&LDS[VTH + ((U) * 16 + l15) * 72 + pos0] = pk;             \
  } while (0)

__global__ __launch_bounds__(256, 4) void k_fused(
    const float* __restrict__ x, const u16* __restrict__ wbf,
    const int* __restrict__ shiftp, float* __restrict__ out) {
  __shared__ u16 LDS[LDS_TOT];
  // XCD-locality swizzle: the 8 windows sharing x/out cache lines (same b,wh)
  // get block IDs congruent mod 128 -> same XCD under round-robin dispatch.
  const int blk = blockIdx.x;
  const int win = ((blk & 127) << 3) | (blk >> 7);  // b*64 + wh*8 + ww
  const int b = win >> 6, wh = (win >> 3) & 7, ww = win & 7;
  const int off = (shiftp[0] != 0) ? 4 : 0;
  const int t = threadIdx.x;

  // Phase-stagger co-resident blocks (slots blk, blk+256, ... share a CU) by
  // ~quarter unit-periods to break the barrier convoy: decorrelated blocks
  // overlap one block's MFMA with another's DMA/VALU.
  {
    const int slot = (blk >> 8) & 3;
    if (slot == 1) __builtin_amdgcn_s_sleep(16);
    else if (slot == 2) __builtin_amdgcn_s_sleep(32);
    else if (slot == 3) __builtin_amdgcn_s_sleep(48);
  }

  // ---- phase 1: stage rolled X into LDS [pos][c] (f32 -> bf16) ----
  {
    u16* X = LDS + XB;
    const int wr = t & 7;
    const int h = ((wh << 3) + wr + off) & 63;
    const int w0 = ((ww << 3) + off) & 63;  // 4-aligned -> no wrap inside run
    const int w1 = ((ww << 3) + off + 4) & 63;
    const int p0 = wr << 3;
#pragma unroll
    for (int it = 0; it < 8; ++it) {
      const int c = (t >> 3) + (it << 5);
      const float* src = x + ((size_t)(b * 256 + c) * 64 + h) * 64;
      float4 v0 = *(const float4*)(src + w0);
      float4 v1 = *(const float4*)(src + w1);
      X[(p0 + 0) * 264 + c] = f2bf(v0.x);
      X[(p0 + 1) * 264 + c] = f2bf(v0.y);
      X[(p0 + 2) * 264 + c] = f2bf(v0.z);
      X[(p0 + 3) * 264 + c] = f2bf(v0.w);
      X[(p0 + 4) * 264 + c] = f2bf(v1.x);
      X[(p0 + 5) * 264 + c] = f2bf(v1.y);
      X[(p0 + 6) * 264 + c] = f2bf(v1.z);
      X[(p0 + 7) * 264 + c] = f2bf(v1.w);
    }
  }
  __syncthreads();  // X ready (full drain OK; also drains x loads -> vmcnt 0)

  const int lane = t & 63, wv = t >> 6;  // wave wv owns pos rows wv*16..+15
  const int l15 = lane & 15, quad = lane >> 4;
  const int pos0 = wv * 16 + quad * 4;

  bf16x8 af[8];
#pragma unroll
  for (int k = 0; k < 8; ++k)
    af[k] = *(const bf16x8*)&LDS[XB + (wv * 16 + l15) * 264 + quad * 8 + k * 32];
  asm volatile("s_waitcnt lgkmcnt(0)" ::: "memory");
  __builtin_amdgcn_s_barrier();  // X fully read everywhere; overlays now free
  MEMF();

  // prologue: stage unit 0 (h0 Q u0) -> BUF0
  stage_half(wbf, LDS + BUF0, t);

  f32x4 accP[16];  // proj acc: tile mt rows quad*4+r (c_out), col l15 (pos)
#pragma unroll
  for (int mt = 0; mt < 16; ++mt) accP[mt] = (f32x4){0.f, 0.f, 0.f, 0.f};

  const float scale = 0.17677669529663687f;  // 1/sqrt(32)
  u16* Pw = LDS + PH + wv * 1152;            // per-wave P [16][72]
  bf16x8 bo;                                 // O fragment, live across u6->u7

  // 64 pipeline units (8 per head), ONE barrier each. Unit g:
  //   {vmcnt(0)+lgkmcnt(0); s_barrier; stage(g+1 -> other buf); compute(g)}
  // The stage issued at unit g start targets the buffer unit g-1 just read
  // (entry drain+barrier makes that safe) and is consumed at unit g+1 after
  // a full unit of flight time.
#pragma unroll 1
  for (int h = 0; h < 8; ++h) {
    // ---- u0: Q u0 (BUF0) ----
    ENTRY();
    stage_half(wbf + (size_t)(h * 2 + 1) * 4096, LDS + BUF1, t);  // Q u1
    QKV_TILE(BUF0, QH, 0);
    // ---- u1: Q u1 (BUF1) ----
    ENTRY();
    stage_half(wbf + (size_t)(16 + h * 2) * 4096, LDS + BUF0, t);  // K u0
    QKV_TILE(BUF1, QH, 1);
    // ---- u2: K u0 (BUF0) ----
    ENTRY();
    stage_half(wbf + (size_t)(17 + h * 2) * 4096, LDS + BUF1, t);  // K u1
    QKV_TILE(BUF0, KH, 0);
    // ---- u3: K u1 (BUF1) ----
    ENTRY();
    stage_half(wbf + (size_t)(32 + h * 2) * 4096, LDS + BUF0, t);  // V u0
    QKV_TILE(BUF1, KH, 1);
    // ---- u4: V u0 (BUF0) ----
    ENTRY();
    stage_half(wbf + (size_t)(33 + h * 2) * 4096, LDS + BUF1, t);  // V u1
    V_TILE(BUF0, 0);
    // ---- u5: V u1 (BUF1) ----
    ENTRY();
    stage_half(wbf + 196608 + (size_t)h * 8192, LDS + BUF0, t);    // pj0
    V_TILE(BUF1, 1);
    // ---- u6: attention (Q/K/V published by entry barrier) + proj 0..7 ----
    ENTRY();
    stage_half(wbf + 196608 + (size_t)h * 8192 + 4096, LDS + BUF1, t);  // pj1
    {
      bf16x8 aq = *(const bf16x8*)&LDS[QH + (wv * 16 + l15) * 40 + quad * 8];
      f32x4 sc[4];
#pragma unroll
      for (int nt = 0; nt < 4; ++nt) {
        bf16x8 bk = *(const bf16x8*)&LDS[KH + (nt * 16 + l15) * 40 + quad * 8];
        f32x4 z = {0.f, 0.f, 0.f, 0.f};
        sc[nt] = __builtin_amdgcn_mfma_f32_16x16x32_bf16(aq, bk, z, 0, 0, 0);
      }
#pragma unroll
      for (int r = 0; r < 4; ++r) {
        float mx = -1e30f;
#pragma unroll
        for (int nt = 0; nt < 4; ++nt) mx = fmaxf(mx, sc[nt][r]);
        mx = fmaxf(mx, __shfl_xor(mx, 1));
        mx = fmaxf(mx, __shfl_xor(mx, 2));
        mx = fmaxf(mx, __shfl_xor(mx, 4));
        mx = fmaxf(mx, __shfl_xor(mx, 8));  // row spans the 16-lane group
        float p[4], sum = 0.f;
#pragma unroll
        for (int nt = 0; nt < 4; ++nt) {
          p[nt] = __expf((sc[nt][r] - mx) * scale);
          sum += p[nt];
        }
        sum += __shfl_xor(sum, 1);
        sum += __shfl_xor(sum, 2);
        sum += __shfl_xor(sum, 4);
        sum += __shfl_xor(sum, 8);
        const float is = 1.f / sum;
#pragma unroll
        for (int nt = 0; nt < 4; ++nt)
          Pw[(quad * 4 + r) * 72 + nt * 16 + l15] = f2bf(p[nt] * is);
      }
      // PV (P write->read same wave: DS ops are in-order per wave)
      f32x4 oa[2];
      oa[0] = (f32x4){0.f, 0.f, 0.f, 0.f};
      oa[1] = (f32x4){0.f, 0.f, 0.f, 0.f};
#pragma unroll
      for (int kk = 0; kk < 2; ++kk) {
        bf16x8 ap = *(const bf16x8*)&Pw[l15 * 72 + kk * 32 + quad * 8];
#pragma unroll
        for (int n2 = 0; n2 < 2; ++n2) {
          bf16x8 bv =
              *(const bf16x8*)&LDS[VTH + (n2 * 16 + l15) * 72 + kk * 32 + quad * 8];
          oa[n2] = __builtin_amdgcn_mfma_f32_16x16x32_bf16(ap, bv, oa[n2], 0, 0, 0);
        }
      }
      // O overwrites own Q rows (wave-private)
#pragma unroll
      for (int n2 = 0; n2 < 2; ++n2)
#pragma unroll
        for (int r = 0; r < 4; ++r)
          LDS[QH + (pos0 + r) * 40 + n2 * 16 + l15] = f2bf(oa[n2][r]);
      // proj accumulate, first half: A = Wproj tiles 0..7 (BUF0), B = O rows
      bo = *(const bf16x8*)&LDS[QH + (wv * 16 + l15) * 40 + quad * 8];
#pragma unroll
      for (int mt = 0; mt < 8; ++mt) {
        bf16x8 aw = *(const bf16x8*)&LDS[BUF0 + mt * 512 + lane * 8];
        accP[mt] = __builtin_amdgcn_mfma_f32_16x16x32_bf16(aw, bo, accP[mt], 0, 0, 0);
      }
    }
    // ---- u7: proj 8..15 (BUF1) ----
    ENTRY();
    if (h < 7)
      stage_half(wbf + (size_t)((h + 1) * 2) * 4096, LDS + BUF0, t);  // next Q u0
#pragma unroll
    for (int mt = 0; mt < 8; ++mt) {
      bf16x8 aw = *(const bf16x8*)&LDS[BUF1 + mt * 512 + lane * 8];
      accP[8 + mt] =
          __builtin_amdgcn_mfma_f32_16x16x32_bf16(aw, bo, accP[8 + mt], 0, 0, 0);
    }
  }

  // ---- epilogue: C[c_out][pos] -> out[b][c][h][w] with roll(+4,+4) ----
  const int pos = wv * 16 + l15;
  const int hco = ((wh << 3) + (pos >> 3) + off) & 63;
  const int wco = ((ww << 3) + (pos & 7) + off) & 63;
#pragma unroll
  for (int mt = 0; mt < 16; ++mt)
#pragma unroll
    for (int r = 0; r < 4; ++r) {
      const int c = mt * 16 + quad * 4 + r;
      out[((size_t)(b * 256 + c) << 12) + (hco << 6) + wco] = accP[mt][r];
    }
}

extern "C" void kernel_launch(void* const* d_in, const int* in_sizes, int n_in,
                              void* d_out, int out_size, void* d_ws, size_t ws_size,
                              hipStream_t stream) {
  const float* x = (const float*)d_in[0];      // [16,256,64,64] f32
  const float* wqkv = (const float*)d_in[1];   // [768,256] f32
  const float* wproj = (const float*)d_in[2];  // [256,256] f32
  const int* shiftp = (const int*)d_in[3];     // scalar
  float* outp = (float*)d_out;                 // [16,256,64,64] f32
  u16* wbf = (u16*)d_ws;                       // 262144 u16 = 512 KB scratch
  hipLaunchKernelGGL(k_conv, dim3(128), dim3(256), 0, stream, wqkv, wproj, wbf);
  hipLaunchKernelGGL(k_fused, dim3(1024), dim3(256), 0, stream, x, wbf, shiftp, outp);
}